// Round 3
// baseline (734.442 us; speedup 1.0000x reference)
//
#include <hip/hip_runtime.h>

#define N_NODES  200000
#define N_CHILD  32
#define N_LAYERS 8

using i4 = __attribute__((ext_vector_type(4))) int;

// One thread per node; 32 random 4B gathers per thread served from L2 via
// non-temporal loads (bypass the 32KB L1 whose ~32 miss slots were the
// 6 cyc/gather bottleneck in R1).
__global__ __launch_bounds__(256) void layer_kernel(
    const float* __restrict__ vals_in,
    float*       __restrict__ vals_out,
    const int*   __restrict__ child_idx,   // [N_NODES][N_CHILD] this layer
    const int*   __restrict__ fun_ids,     // [N_NODES] this layer
    const float* __restrict__ wptr)
{
    int node = blockIdx.x * blockDim.x + threadIdx.x;
    if (node >= N_NODES) return;

    const i4* ci = (const i4*)(child_idx + (size_t)node * N_CHILD);

    // Two independent accumulators; loads are all independent so the
    // compiler can keep ~32 nt loads in flight per thread.
    float s0 = 0.0f, s1 = 0.0f;
#pragma unroll
    for (int j = 0; j < N_CHILD / 4; ++j) {
        i4 c = __builtin_nontemporal_load(ci + j);
        s0 += __builtin_nontemporal_load(vals_in + c.x);
        s1 += __builtin_nontemporal_load(vals_in + c.y);
        s0 += __builtin_nontemporal_load(vals_in + c.z);
        s1 += __builtin_nontemporal_load(vals_in + c.w);
    }
    float s = s0 + s1;

    float x = wptr[0] * s;
    int fid = fun_ids[node];
    float y;
    if (fid == 0)      y = tanhf(x);
    else if (fid == 1) y = 1.0f / (1.0f + __expf(-x));  // safe at +-inf
    else if (fid == 2) y = fmaxf(x, 0.0f);
    else               y = x;
    vals_out[node] = y;
}

extern "C" void kernel_launch(void* const* d_in, const int* in_sizes, int n_in,
                              void* d_out, int out_size, void* d_ws, size_t ws_size,
                              hipStream_t stream) {
    const float* X         = (const float*)d_in[0];
    const float* w         = (const float*)d_in[1];
    const int*   child_idx = (const int*)d_in[2];
    const int*   fun_ids   = (const int*)d_in[3];
    float*       out       = (float*)d_out;
    float*       bufA      = (float*)d_ws;   // 800 KB ping buffer

    const int threads = 256;
    const int blocks  = (N_NODES + threads - 1) / threads;

    const float* cur = X;
    for (int l = 0; l < N_LAYERS; ++l) {
        // even layers -> bufA, odd layers -> d_out; layer 7 (last) -> d_out
        float* nxt = (l & 1) ? out : bufA;
        layer_kernel<<<blocks, threads, 0, stream>>>(
            cur, nxt,
            child_idx + (size_t)l * N_NODES * N_CHILD,
            fun_ids   + (size_t)l * N_NODES,
            w);
        cur = nxt;
    }
}

// Round 4
// 542.594 us; speedup vs baseline: 1.3536x; 1.3536x over previous
//
#include <hip/hip_runtime.h>

#define N_NODES  200000
#define N_CHILD  32
#define N_LAYERS 8
#define CHUNK    32768                               // floats per LDS chunk = 128 KB
#define NCHUNK   ((N_NODES + CHUNK - 1) / CHUNK)     // 7
#define NB       256                                 // 1 block per CU
#define NPB      ((N_NODES + NB - 1) / NB)           // 782 nodes per block
#define BT       832                                 // 13 waves; 782/832 = 94% active

// Sweep the 800 KB value table through a 128 KB LDS window (7 chunks).
// Each thread holds its node's 32 child indices in registers; per chunk,
// membership test = sub + unsigned-compare, hit = one exec-masked ds_read.
// LDS serves random 4B words ~40x faster per address than the global TA path
// that limited R1 (6 cyc/lane-address).
__global__ __launch_bounds__(BT) void layer_kernel(
    const float* __restrict__ vals_in,
    float*       __restrict__ vals_out,
    const int*   __restrict__ child_idx,   // [N_NODES][N_CHILD] this layer
    const int*   __restrict__ fun_ids,     // [N_NODES] this layer
    const float* __restrict__ wptr)
{
    __shared__ float lds[CHUNK];
    const int tid    = threadIdx.x;
    const int node   = blockIdx.x * NPB + tid;
    const bool active = (tid < NPB) && (node < N_NODES);

    // child indices -> registers (8x int4, coalesced)
    int idx[N_CHILD];
    int fid = 3;
    if (active) {
        const int4* ci = (const int4*)(child_idx + (size_t)node * N_CHILD);
        #pragma unroll
        for (int j = 0; j < N_CHILD / 4; ++j) {
            int4 c = ci[j];
            idx[4*j+0] = c.x; idx[4*j+1] = c.y;
            idx[4*j+2] = c.z; idx[4*j+3] = c.w;
        }
        fid = fun_ids[node];
    } else {
        #pragma unroll
        for (int j = 0; j < N_CHILD; ++j) idx[j] = 0;
    }

    float s = 0.0f;
    const float4* __restrict__ src4 = (const float4*)vals_in;
    #pragma unroll 1
    for (int c = 0; c < NCHUNK; ++c) {
        __syncthreads();   // previous pass done reading LDS
        {
            const int base  = c * CHUNK;
            const int n4    = min(CHUNK, N_NODES - base) >> 2;   // both %4==0
            const int base4 = base >> 2;
            float4* dst = (float4*)lds;
            for (int i = tid; i < n4; i += BT) dst[i] = src4[base4 + i];
        }
        __syncthreads();   // chunk staged
        if (active) {
            const unsigned cbase = (unsigned)(c * CHUNK);
            #pragma unroll
            for (int j = 0; j < N_CHILD; ++j) {
                unsigned off = (unsigned)idx[j] - cbase;
                if (off < CHUNK) s += lds[off];
            }
        }
    }

    if (active) {
        float x = wptr[0] * s;
        float y;
        if (fid == 0)      y = tanhf(x);
        else if (fid == 1) y = 1.0f / (1.0f + __expf(-x));  // safe at +-inf
        else if (fid == 2) y = fmaxf(x, 0.0f);
        else               y = x;
        vals_out[node] = y;
    }
}

extern "C" void kernel_launch(void* const* d_in, const int* in_sizes, int n_in,
                              void* d_out, int out_size, void* d_ws, size_t ws_size,
                              hipStream_t stream) {
    const float* X         = (const float*)d_in[0];
    const float* w         = (const float*)d_in[1];
    const int*   child_idx = (const int*)d_in[2];
    const int*   fun_ids   = (const int*)d_in[3];
    float*       out       = (float*)d_out;
    float*       bufA      = (float*)d_ws;   // 800 KB ping buffer

    const float* cur = X;
    for (int l = 0; l < N_LAYERS; ++l) {
        // even layers -> bufA, odd layers -> d_out; layer 7 (last) -> d_out
        float* nxt = (l & 1) ? out : bufA;
        layer_kernel<<<NB, BT, 0, stream>>>(
            cur, nxt,
            child_idx + (size_t)l * N_NODES * N_CHILD,
            fun_ids   + (size_t)l * N_NODES,
            w);
        cur = nxt;
    }
}